// Round 11
// baseline (1074.865 us; speedup 1.0000x reference)
//
#include <hip/hip_runtime.h>

#define HH 192
#define WW 192
#define HWPIX (HH * WW)

typedef __attribute__((ext_vector_type(8))) short bf16x8;
typedef __attribute__((ext_vector_type(4))) float f32x4;
typedef __attribute__((ext_vector_type(4))) unsigned int u32x4;

__device__ __forceinline__ unsigned f2bf(float f) {
    unsigned u = __builtin_bit_cast(unsigned, f);
    return (u + 0x7FFFu + ((u >> 16) & 1u)) >> 16;
}

__device__ __forceinline__ unsigned cvtpk(float lo, float hi) {
    unsigned r;
    asm("v_cvt_pk_bf16_f32 %0, %1, %2" : "=v"(r) : "v"(lo), "v"(hi));
    return r;
}

// ---------------- weight fusion (r9 layout, proven) ----------------
// frag = ((cc*3 + kw)*3 + kh)*8 + ow ; within frag: ln*8 + j  (shorts)
// ow=o>>4, ln=((c>>3)&3)*16+(o&15), j=c&7, cc=c>>5
__global__ void fuse_weights(const float* __restrict__ wsq, const float* __restrict__ wv,
                             const float* __restrict__ whr, const float* __restrict__ w19,
                             const float* __restrict__ w37, unsigned short* __restrict__ wbuf) {
    int idx = blockIdx.x * 256 + threadIdx.x;
    if (idx >= 128 * 128 * 9) return;
    int o = idx / 1152;
    int r = idx - o * 1152;
    int c = r / 9;
    int tap = r - c * 9;
    int kh = tap / 3, kw = tap - kh * 3;
    float v = wsq[((o * 128 + c) * 3 + kh) * 3 + kw];
    if (kw == 1) v += wv[(o * 128 + c) * 3 + kh];
    if (kh == 1) v += whr[(o * 128 + c) * 3 + kw];
    if (kh == kw) v += w19[((o * 128 + c) * 3 + kh) * 3 + kw];
    if (kh + kw == 2) v += w37[((o * 128 + c) * 3 + kh) * 3 + kw];
    int cc = c >> 5, ow = o >> 4;
    int ln = ((c >> 3) & 3) * 16 + (o & 15);
    int j = c & 7;
    int frag = ((cc * 3 + kw) * 3 + kh) * 8 + ow;
    wbuf[(size_t)frag * 512 + ln * 8 + j] = (unsigned short)f2bf(v);
}

// ---------------- barrier-free direct-from-global conv (r9 + reg diet) ----
// Block: 16x16 out px, 128 o, 4 independent waves (ni = 4-row band).
// NO LDS, NO barriers. Per iter (cc,kw) of 12: build 6 B-frags from global
// with a ROLLING 2-row buffer (rows r+1,r+2 in flight while packing row r;
// fv live = 16 regs vs r9's 48), pack via v_cvt_pk_bf16_f32 + OOB zeroing,
// then 8 ow x 12 MFMA with weight frags streamed from L1/L2.
// ghc/hok are wave-uniform -> SGPRs. Target: <=170 regs -> 3 waves/SIMD.
__global__ __launch_bounds__(256, 3) void convg(const float* __restrict__ x,
                                                const unsigned short* __restrict__ wbuf,
                                                float* __restrict__ out) {
    const int t = threadIdx.x, l = t & 63, ni = t >> 6;
    const int l15 = l & 15, l4 = l >> 4;

    // XCD-chunked bijective swizzle: 2304 = 8 x 288 (= 2 full batches/XCD).
    int id = (int)blockIdx.x;
    int id2 = (id & 7) * 288 + (id >> 3);
    int b = id2 / 144;
    int rem = id2 - b * 144;
    int by = rem / 12, bx = rem - by * 12;
    const int h0 = by * 16, w0 = bx * 16;

    const float* __restrict__ xb = x + (size_t)b * (128 * HWPIX);

    f32x4 acc[8][4];
    const f32x4 zero = {0.f, 0.f, 0.f, 0.f};
#pragma unroll
    for (int ow = 0; ow < 8; ++ow)
#pragma unroll
        for (int np = 0; np < 4; ++np) acc[ow][np] = zero;

    // input rows for this wave: gh = h0 + 4*ni - 1 + rid, rid 0..5 (wave-uniform)
    int ghc[6], hok[6];
#pragma unroll
    for (int rid = 0; rid < 6; ++rid) {
        int gh = h0 + 4 * ni - 1 + rid;
        hok[rid] = (unsigned)gh < (unsigned)HH;
        ghc[rid] = min(max(gh, 0), HH - 1);
    }

    float fvA[8], fvB[8];
    bf16x8 Bc[6];

#define LOADROW(IT, RID, SV)                                                             \
    {                                                                                    \
        int cc_ = (IT) / 3, kw_ = (IT) - 3 * cc_;                                        \
        int gw = w0 - 1 + kw_ + l15;                                                     \
        int gwc = min(max(gw, 0), WW - 1);                                               \
        const float* p_ =                                                                \
            xb + (size_t)(cc_ * 32 + l4 * 8) * HWPIX + ghc[RID] * WW + gwc;              \
        _Pragma("unroll") for (int j = 0; j < 8; ++j) SV[j] = p_[(size_t)j * HWPIX];     \
    }

#define PACKROW(IT, RID, SV)                                                             \
    {                                                                                    \
        int cc_ = (IT) / 3, kw_ = (IT) - 3 * cc_;                                        \
        (void)cc_;                                                                       \
        int gw = w0 - 1 + kw_ + l15;                                                     \
        int ok = ((unsigned)gw < (unsigned)WW) & hok[RID];                               \
        u32x4 pk;                                                                        \
        _Pragma("unroll") for (int q = 0; q < 4; ++q) {                                  \
            unsigned v_ = cvtpk(SV[2 * q], SV[2 * q + 1]);                               \
            pk[q] = ok ? v_ : 0u;                                                        \
        }                                                                                \
        Bc[RID] = __builtin_bit_cast(bf16x8, pk);                                        \
    }

#define MMI(IT)                                                                          \
    {                                                                                    \
        int cc_ = (IT) / 3, kw_ = (IT) - 3 * cc_;                                        \
        const unsigned short* wp =                                                       \
            wbuf + (size_t)((cc_ * 3 + kw_) * 3) * 8 * 512 + l * 8;                      \
        _Pragma("unroll") for (int ow = 0; ow < 8; ++ow) {                               \
            bf16x8 a0 = *(const bf16x8*)(wp + (0 * 8 + ow) * 512);                       \
            bf16x8 a1 = *(const bf16x8*)(wp + (1 * 8 + ow) * 512);                       \
            bf16x8 a2 = *(const bf16x8*)(wp + (2 * 8 + ow) * 512);                       \
            _Pragma("unroll") for (int np = 0; np < 4; ++np)                             \
                acc[ow][np] = __builtin_amdgcn_mfma_f32_16x16x32_bf16(                   \
                    a0, Bc[np + 0], acc[ow][np], 0, 0, 0);                               \
            _Pragma("unroll") for (int np = 0; np < 4; ++np)                             \
                acc[ow][np] = __builtin_amdgcn_mfma_f32_16x16x32_bf16(                   \
                    a1, Bc[np + 1], acc[ow][np], 0, 0, 0);                               \
            _Pragma("unroll") for (int np = 0; np < 4; ++np)                             \
                acc[ow][np] = __builtin_amdgcn_mfma_f32_16x16x32_bf16(                   \
                    a2, Bc[np + 2], acc[ow][np], 0, 0, 0);                               \
        }                                                                                \
    }

#pragma unroll 1
    for (int it = 0; it < 12; ++it) {
        LOADROW(it, 0, fvA)
        LOADROW(it, 1, fvB)
        PACKROW(it, 0, fvA)
        LOADROW(it, 2, fvA)
        PACKROW(it, 1, fvB)
        LOADROW(it, 3, fvB)
        PACKROW(it, 2, fvA)
        LOADROW(it, 4, fvA)
        PACKROW(it, 3, fvB)
        LOADROW(it, 5, fvB)
        PACKROW(it, 4, fvA)
        PACKROW(it, 5, fvB)
        MMI(it)
    }

    // epilogue: D row=(l>>4)*4+j -> o, col=l&15 -> w; wave's rows = 4*ni+np
    float* __restrict__ ob =
        out + (size_t)b * (128 * HWPIX) + (size_t)(h0 + 4 * ni) * WW + w0 + l15;
#pragma unroll
    for (int ow = 0; ow < 8; ++ow) {
#pragma unroll
        for (int j = 0; j < 4; ++j) {
            int o = ow * 16 + l4 * 4 + j;
            float* op = ob + (size_t)o * HWPIX;
#pragma unroll
            for (int np = 0; np < 4; ++np)
                op[np * WW] = acc[ow][np][j];
        }
    }
}

extern "C" void kernel_launch(void* const* d_in, const int* in_sizes, int n_in,
                              void* d_out, int out_size, void* d_ws, size_t ws_size,
                              hipStream_t stream) {
    const float* x   = (const float*)d_in[0];
    const float* wsq = (const float*)d_in[1];
    const float* wvv = (const float*)d_in[2];
    const float* wh  = (const float*)d_in[3];
    const float* w19 = (const float*)d_in[4];
    const float* w37 = (const float*)d_in[5];

    unsigned short* wbuf = (unsigned short*)d_ws;  // 294,912 B

    fuse_weights<<<576, 256, 0, stream>>>(wsq, wvv, wh, w19, w37, wbuf);
    convg<<<2304, 256, 0, stream>>>(x, wbuf, (float*)d_out);
}

// Round 12
// 1068.451 us; speedup vs baseline: 1.0060x; 1.0060x over previous
//
#include <hip/hip_runtime.h>

#define HH 192
#define WW 192
#define HWPIX (HH * WW)

typedef __attribute__((ext_vector_type(8))) short bf16x8;
typedef __attribute__((ext_vector_type(4))) float f32x4;
typedef __attribute__((ext_vector_type(4))) unsigned int u32x4;

__device__ __forceinline__ unsigned f2bf(float f) {
    unsigned u = __builtin_bit_cast(unsigned, f);
    return (u + 0x7FFFu + ((u >> 16) & 1u)) >> 16;
}

__device__ __forceinline__ unsigned cvtpk(float lo, float hi) {
    unsigned r;
    asm("v_cvt_pk_bf16_f32 %0, %1, %2" : "=v"(r) : "v"(lo), "v"(hi));
    return r;
}

// ---------------- weight fusion (r9 layout, proven) ----------------
// frag = ((cc*3 + kw)*3 + kh)*8 + ow ; within frag: ln*8 + j  (shorts)
// ow=o>>4, ln=((c>>3)&3)*16+(o&15), j=c&7, cc=c>>5
__global__ void fuse_weights(const float* __restrict__ wsq, const float* __restrict__ wv,
                             const float* __restrict__ whr, const float* __restrict__ w19,
                             const float* __restrict__ w37, unsigned short* __restrict__ wbuf) {
    int idx = blockIdx.x * 256 + threadIdx.x;
    if (idx >= 128 * 128 * 9) return;
    int o = idx / 1152;
    int r = idx - o * 1152;
    int c = r / 9;
    int tap = r - c * 9;
    int kh = tap / 3, kw = tap - kh * 3;
    float v = wsq[((o * 128 + c) * 3 + kh) * 3 + kw];
    if (kw == 1) v += wv[(o * 128 + c) * 3 + kh];
    if (kh == 1) v += whr[(o * 128 + c) * 3 + kw];
    if (kh == kw) v += w19[((o * 128 + c) * 3 + kh) * 3 + kw];
    if (kh + kw == 2) v += w37[((o * 128 + c) * 3 + kh) * 3 + kw];
    int cc = c >> 5, ow = o >> 4;
    int ln = ((c >> 3) & 3) * 16 + (o & 15);
    int j = c & 7;
    int frag = ((cc * 3 + kw) * 3 + kh) * 8 + ow;
    wbuf[(size_t)frag * 512 + ln * 8 + j] = (unsigned short)f2bf(v);
}

// ---------------- barrier-free direct-from-global conv (r9 + reg diet) ----
// Block: 16x16 out px, 128 o, 4 independent waves (ni = 4-row band).
// NO LDS, NO barriers. Per iter (cc,kw) of 12: build 6 B-frags from global
// with a ROLLING 2-row buffer (rows r+1,r+2 in flight while packing row r;
// fv live = 16 regs vs r9's 48), pack via v_cvt_pk_bf16_f32 + OOB zeroing,
// then 8 ow x 12 MFMA with weight frags streamed from L1/L2.
// ghc/hok are wave-uniform -> SGPRs. Target: <=170 regs -> 3 waves/SIMD.
__global__ __launch_bounds__(256, 3) void convg(const float* __restrict__ x,
                                                const unsigned short* __restrict__ wbuf,
                                                float* __restrict__ out) {
    const int t = threadIdx.x, l = t & 63, ni = t >> 6;
    const int l15 = l & 15, l4 = l >> 4;

    // XCD-chunked bijective swizzle: 2304 = 8 x 288 (= 2 full batches/XCD).
    int id = (int)blockIdx.x;
    int id2 = (id & 7) * 288 + (id >> 3);
    int b = id2 / 144;
    int rem = id2 - b * 144;
    int by = rem / 12, bx = rem - by * 12;
    const int h0 = by * 16, w0 = bx * 16;

    const float* __restrict__ xb = x + (size_t)b * (128 * HWPIX);

    f32x4 acc[8][4];
    const f32x4 zero = {0.f, 0.f, 0.f, 0.f};
#pragma unroll
    for (int ow = 0; ow < 8; ++ow)
#pragma unroll
        for (int np = 0; np < 4; ++np) acc[ow][np] = zero;

    // input rows for this wave: gh = h0 + 4*ni - 1 + rid, rid 0..5 (wave-uniform)
    int ghc[6], hok[6];
#pragma unroll
    for (int rid = 0; rid < 6; ++rid) {
        int gh = h0 + 4 * ni - 1 + rid;
        hok[rid] = (unsigned)gh < (unsigned)HH;
        ghc[rid] = min(max(gh, 0), HH - 1);
    }

    float fvA[8], fvB[8];
    bf16x8 Bc[6];

#define LOADROW(IT, RID, SV)                                                             \
    {                                                                                    \
        int cc_ = (IT) / 3, kw_ = (IT) - 3 * cc_;                                        \
        int gw = w0 - 1 + kw_ + l15;                                                     \
        int gwc = min(max(gw, 0), WW - 1);                                               \
        const float* p_ =                                                                \
            xb + (size_t)(cc_ * 32 + l4 * 8) * HWPIX + ghc[RID] * WW + gwc;              \
        _Pragma("unroll") for (int j = 0; j < 8; ++j) SV[j] = p_[(size_t)j * HWPIX];     \
    }

#define PACKROW(IT, RID, SV)                                                             \
    {                                                                                    \
        int cc_ = (IT) / 3, kw_ = (IT) - 3 * cc_;                                        \
        (void)cc_;                                                                       \
        int gw = w0 - 1 + kw_ + l15;                                                     \
        int ok = ((unsigned)gw < (unsigned)WW) & hok[RID];                               \
        u32x4 pk;                                                                        \
        _Pragma("unroll") for (int q = 0; q < 4; ++q) {                                  \
            unsigned v_ = cvtpk(SV[2 * q], SV[2 * q + 1]);                               \
            pk[q] = ok ? v_ : 0u;                                                        \
        }                                                                                \
        Bc[RID] = __builtin_bit_cast(bf16x8, pk);                                        \
    }

#define MMI(IT)                                                                          \
    {                                                                                    \
        int cc_ = (IT) / 3, kw_ = (IT) - 3 * cc_;                                        \
        const unsigned short* wp =                                                       \
            wbuf + (size_t)((cc_ * 3 + kw_) * 3) * 8 * 512 + l * 8;                      \
        _Pragma("unroll") for (int ow = 0; ow < 8; ++ow) {                               \
            bf16x8 a0 = *(const bf16x8*)(wp + (0 * 8 + ow) * 512);                       \
            bf16x8 a1 = *(const bf16x8*)(wp + (1 * 8 + ow) * 512);                       \
            bf16x8 a2 = *(const bf16x8*)(wp + (2 * 8 + ow) * 512);                       \
            _Pragma("unroll") for (int np = 0; np < 4; ++np)                             \
                acc[ow][np] = __builtin_amdgcn_mfma_f32_16x16x32_bf16(                   \
                    a0, Bc[np + 0], acc[ow][np], 0, 0, 0);                               \
            _Pragma("unroll") for (int np = 0; np < 4; ++np)                             \
                acc[ow][np] = __builtin_amdgcn_mfma_f32_16x16x32_bf16(                   \
                    a1, Bc[np + 1], acc[ow][np], 0, 0, 0);                               \
            _Pragma("unroll") for (int np = 0; np < 4; ++np)                             \
                acc[ow][np] = __builtin_amdgcn_mfma_f32_16x16x32_bf16(                   \
                    a2, Bc[np + 2], acc[ow][np], 0, 0, 0);                               \
        }                                                                                \
    }

#pragma unroll 1
    for (int it = 0; it < 12; ++it) {
        LOADROW(it, 0, fvA)
        LOADROW(it, 1, fvB)
        PACKROW(it, 0, fvA)
        LOADROW(it, 2, fvA)
        PACKROW(it, 1, fvB)
        LOADROW(it, 3, fvB)
        PACKROW(it, 2, fvA)
        LOADROW(it, 4, fvA)
        PACKROW(it, 3, fvB)
        LOADROW(it, 5, fvB)
        PACKROW(it, 4, fvA)
        PACKROW(it, 5, fvB)
        MMI(it)
    }

    // epilogue: D row=(l>>4)*4+j -> o, col=l&15 -> w; wave's rows = 4*ni+np
    float* __restrict__ ob =
        out + (size_t)b * (128 * HWPIX) + (size_t)(h0 + 4 * ni) * WW + w0 + l15;
#pragma unroll
    for (int ow = 0; ow < 8; ++ow) {
#pragma unroll
        for (int j = 0; j < 4; ++j) {
            int o = ow * 16 + l4 * 4 + j;
            float* op = ob + (size_t)o * HWPIX;
#pragma unroll
            for (int np = 0; np < 4; ++np)
                op[np * WW] = acc[ow][np][j];
        }
    }
}

extern "C" void kernel_launch(void* const* d_in, const int* in_sizes, int n_in,
                              void* d_out, int out_size, void* d_ws, size_t ws_size,
                              hipStream_t stream) {
    const float* x   = (const float*)d_in[0];
    const float* wsq = (const float*)d_in[1];
    const float* wvv = (const float*)d_in[2];
    const float* wh  = (const float*)d_in[3];
    const float* w19 = (const float*)d_in[4];
    const float* w37 = (const float*)d_in[5];

    unsigned short* wbuf = (unsigned short*)d_ws;  // 294,912 B

    fuse_weights<<<576, 256, 0, stream>>>(wsq, wvv, wh, w19, w37, wbuf);
    convg<<<2304, 256, 0, stream>>>(x, wbuf, (float*)d_out);
}

// Round 14
// 298.617 us; speedup vs baseline: 3.5995x; 3.5780x over previous
//
#include <hip/hip_runtime.h>

#define HH 192
#define WW 192
#define HWPIX (HH * WW)
#define NPX 180              // 10 x 18 halo pixels
#define PLANE 2880           // 180 px * 16 B per c-octet plane
#define CHUNKB 11520         // 4 planes per 32c chunk

typedef __attribute__((ext_vector_type(8))) short bf16x8;
typedef __attribute__((ext_vector_type(4))) float f32x4;
typedef __attribute__((ext_vector_type(4))) unsigned int u32x4;

__device__ __forceinline__ unsigned f2bf(float f) {
    unsigned u = __builtin_bit_cast(unsigned, f);
    return (u + 0x7FFFu + ((u >> 16) & 1u)) >> 16;
}

__device__ __forceinline__ unsigned cvtpk(float lo, float hi) {
    unsigned r;
    asm("v_cvt_pk_bf16_f32 %0, %1, %2" : "=v"(r) : "v"(lo), "v"(hi));
    return r;
}

// ---------------- weight fusion (r7 layout, verbatim) ----------------
// frag = ((cc*3 + kw)*2 + mi)*12 + kh*4 + mo ; within frag: ln*8 + j
// mi=o>>6, mo=(o>>4)&3, ln=((c>>3)&3)*16+(o&15), j=c&7, cc=c>>5
__global__ void fuse_weights(const float* __restrict__ wsq, const float* __restrict__ wv,
                             const float* __restrict__ whr, const float* __restrict__ w19,
                             const float* __restrict__ w37, unsigned short* __restrict__ wbuf) {
    int idx = blockIdx.x * 256 + threadIdx.x;
    if (idx >= 128 * 128 * 9) return;
    int o = idx / 1152;
    int r = idx - o * 1152;
    int c = r / 9;
    int tap = r - c * 9;
    int kh = tap / 3, kw = tap - kh * 3;
    float v = wsq[((o * 128 + c) * 3 + kh) * 3 + kw];
    if (kw == 1) v += wv[(o * 128 + c) * 3 + kh];
    if (kh == 1) v += whr[(o * 128 + c) * 3 + kw];
    if (kh == kw) v += w19[((o * 128 + c) * 3 + kh) * 3 + kw];
    if (kh + kw == 2) v += w37[((o * 128 + c) * 3 + kh) * 3 + kw];
    int cc = c >> 5;
    int mi = o >> 6, mo = (o >> 4) & 3;
    int ln = ((c >> 3) & 3) * 16 + (o & 15);
    int j = c & 7;
    int frag = ((cc * 3 + kw) * 2 + mi) * 12 + kh * 4 + mo;
    wbuf[(size_t)frag * 512 + ln * 8 + j] = (unsigned short)f2bf(v);
}

// ---------------- single-pass conv: r7 structure, HALF-HEIGHT tile ----------
// Block: 16x8 out px, 128 o, 4 waves = (mi: o-half, ni: row-half of 4).
// acc = 64 f32/lane (was 128) -> target 3 waves/SIMD via launch_bounds(256,3).
// Staging, LDS layout [slot][px][16B], KWPASS, epilogue: r7 pattern resized.
__global__ __launch_bounds__(256, 3) void conv1(const float* __restrict__ x,
                                                const unsigned short* __restrict__ wbuf,
                                                float* __restrict__ out) {
    __shared__ __align__(1024) unsigned char lds[2 * CHUNKB];
    const int t = threadIdx.x, l = t & 63, wvid = t >> 6;
    const int mi = wvid >> 1, ni = wvid & 1, l15 = l & 15, l4 = l >> 4;

    // XCD-chunked bijective swizzle: 4608 = 8 x 576; 576/XCD = 2 full batches.
    int id = (int)blockIdx.x;
    int id2 = (id & 7) * 576 + (id >> 3);
    int b = id2 / 288;
    int rem = id2 - b * 288;
    int by = rem / 12, bx = rem - by * 12;
    const int h0 = by * 8, w0 = bx * 16;

    const float* __restrict__ xb = x + (size_t)b * (128 * HWPIX);

    f32x4 acc[4][4];
    const f32x4 zero = {0.f, 0.f, 0.f, 0.f};
#pragma unroll
    for (int mo = 0; mo < 4; ++mo)
#pragma unroll
        for (int np = 0; np < 4; ++np) acc[mo][np] = zero;

    float svA[8], svB[8];

    // task idx = t + 256*R < 720: slot = idx/180 (c-octet), px = idx%180
#define LOADR(CC, R, SV)                                                                \
    {                                                                                   \
        int idx_ = t + 256 * (R);                                                       \
        if ((R) < 2 || idx_ < 720) {                                                    \
            int slot_ = idx_ / NPX;                                                     \
            int px_ = idx_ - slot_ * NPX;                                               \
            int ih_ = px_ / 18, iw_ = px_ - ih_ * 18;                                   \
            int gh_ = h0 - 1 + ih_, gw_ = w0 - 1 + iw_;                                 \
            int ghc_ = min(max(gh_, 0), HH - 1);                                        \
            int gwc_ = min(max(gw_, 0), WW - 1);                                        \
            const float* p_ =                                                           \
                xb + (size_t)((CC) * 32 + slot_ * 8) * HWPIX + ghc_ * WW + gwc_;        \
            _Pragma("unroll") for (int j = 0; j < 8; ++j) SV[j] = p_[(size_t)j * HWPIX]; \
        }                                                                               \
    }

#define WRITER(R, BB, SV)                                                               \
    {                                                                                   \
        int idx_ = t + 256 * (R);                                                       \
        if ((R) < 2 || idx_ < 720) {                                                    \
            int slot_ = idx_ / NPX;                                                     \
            int px_ = idx_ - slot_ * NPX;                                               \
            int ih_ = px_ / 18, iw_ = px_ - ih_ * 18;                                   \
            int gh_ = h0 - 1 + ih_, gw_ = w0 - 1 + iw_;                                 \
            int ok_ = ((unsigned)gh_ < (unsigned)HH) & ((unsigned)gw_ < (unsigned)WW);  \
            u32x4 pk;                                                                   \
            _Pragma("unroll") for (int q = 0; q < 4; ++q) {                             \
                unsigned v_ = cvtpk(SV[2 * q], SV[2 * q + 1]);                          \
                pk[q] = ok_ ? v_ : 0u;                                                  \
            }                                                                           \
            *(u32x4*)(lds + (BB) + slot_ * PLANE + px_ * 16) = pk;                      \
        }                                                                               \
    }

#define KWPASS(KW)                                                                      \
    {                                                                                   \
        const unsigned short* wp =                                                      \
            wbuf + (size_t)(((cc * 3 + (KW)) * 2 + mi) * 12) * 512 + l * 8;             \
        bf16x8 a[12];                                                                   \
        _Pragma("unroll") for (int f = 0; f < 12; ++f)                                  \
            a[f] = *(const bf16x8*)(wp + f * 512);                                      \
        _Pragma("unroll") for (int rr = 0; rr < 6; ++rr) {                              \
            bf16x8 bf = *(const bf16x8*)(lds + bb + l4 * PLANE +                        \
                                         (ni * 72 + l15) * 16 + (KW) * 16 + rr * 288); \
            _Pragma("unroll") for (int kh = 0; kh < 3; ++kh) {                          \
                const int np = rr - kh;                                                 \
                if (np >= 0 && np < 4) {                                                \
                    _Pragma("unroll") for (int mo = 0; mo < 4; ++mo)                    \
                        acc[mo][np] = __builtin_amdgcn_mfma_f32_16x16x32_bf16(          \
                            a[kh * 4 + mo], bf, acc[mo][np], 0, 0, 0);                  \
                }                                                                       \
            }                                                                           \
        }                                                                               \
    }

    // prologue: stage chunk 0 into buffer 0
    LOADR(0, 0, svA)
    WRITER(0, 0, svA)
    LOADR(0, 1, svB)
    WRITER(1, 0, svB)
    LOADR(0, 2, svA)
    WRITER(2, 0, svA)
    __syncthreads();

    int bb = 0;
#pragma unroll 1
    for (int cc = 0; cc < 4; ++cc) {
        if (cc < 3) { LOADR(cc + 1, 0, svA) }
        KWPASS(0)
        if (cc < 3) {
            WRITER(0, bb ^ CHUNKB, svA)
            LOADR(cc + 1, 1, svB)
        }
        KWPASS(1)
        if (cc < 3) {
            WRITER(1, bb ^ CHUNKB, svB)
            LOADR(cc + 1, 2, svA)
        }
        KWPASS(2)
        if (cc < 3) { WRITER(2, bb ^ CHUNKB, svA) }
        __syncthreads();
        bb ^= CHUNKB;
    }

    // epilogue: D row=(l>>4)*4+j -> o, col=l&15 -> w; wave rows = ni*4+np
    float* __restrict__ ob = out + (size_t)b * (128 * HWPIX) + (size_t)h0 * WW + w0 + l15;
#pragma unroll
    for (int mo = 0; mo < 4; ++mo) {
#pragma unroll
        for (int j = 0; j < 4; ++j) {
            int o = mi * 64 + mo * 16 + l4 * 4 + j;
            float* op = ob + (size_t)o * HWPIX;
#pragma unroll
            for (int np = 0; np < 4; ++np)
                op[(ni * 4 + np) * WW] = acc[mo][np][j];
        }
    }
}

extern "C" void kernel_launch(void* const* d_in, const int* in_sizes, int n_in,
                              void* d_out, int out_size, void* d_ws, size_t ws_size,
                              hipStream_t stream) {
    const float* x   = (const float*)d_in[0];
    const float* wsq = (const float*)d_in[1];
    const float* wvv = (const float*)d_in[2];
    const float* wh  = (const float*)d_in[3];
    const float* w19 = (const float*)d_in[4];
    const float* w37 = (const float*)d_in[5];

    unsigned short* wbuf = (unsigned short*)d_ws;  // 294,912 B

    fuse_weights<<<576, 256, 0, stream>>>(wsq, wvv, wh, w19, w37, wbuf);
    conv1<<<4608, 256, 0, stream>>>(x, wbuf, (float*)d_out);
}